// Round 1
// baseline (96.442 us; speedup 1.0000x reference)
//
#include <hip/hip_runtime.h>

#define NV 16384
#define NTHREADS 256
#define QPT 8            // queries per thread
#define RC 256           // reference points per chunk (per block)
#define QBLOCKS (NV / (NTHREADS * QPT))   // 8
#define RBLOCKS (NV / RC)                  // 64
#define LOSS_BLOCKS 128

__global__ void init_best_kernel(unsigned long long* __restrict__ best) {
    int i = blockIdx.x * blockDim.x + threadIdx.x;
    if (i < 2 * NV) best[i] = 0xFFFFFFFFFFFFFFFFULL;
}

// For each query point (from qpts), find argmin over a chunk of reference
// points (from rpts) of the metric 0.5*||r||^2 - q.r  (monotone-equivalent to
// squared distance for fixed q). Merge across chunks via packed atomicMin:
// key = (sortable_float_bits(dist) << 32) | ref_index. Lower index wins ties.
__global__ __launch_bounds__(NTHREADS) void nn_kernel(
    const float* __restrict__ qpts, const float* __restrict__ rpts,
    unsigned long long* __restrict__ best)
{
    __shared__ float4 sref[RC];
    const int tid = threadIdx.x;
    const int refbase = blockIdx.y * RC;

    // Stage reference chunk into LDS: (x, y, z, 0.5*||r||^2)
    for (int i = tid; i < RC; i += NTHREADS) {
        float x = rpts[3 * (refbase + i) + 0];
        float y = rpts[3 * (refbase + i) + 1];
        float z = rpts[3 * (refbase + i) + 2];
        sref[i] = make_float4(x, y, z, 0.5f * (x * x + y * y + z * z));
    }
    __syncthreads();

    // Load this thread's queries (negated, so metric = fma chain).
    const int qbase = blockIdx.x * (NTHREADS * QPT);
    float nqx[QPT], nqy[QPT], nqz[QPT];
    float dmin[QPT];
    int imin[QPT];
#pragma unroll
    for (int k = 0; k < QPT; k++) {
        int qi = qbase + k * NTHREADS + tid;
        nqx[k] = -qpts[3 * qi + 0];
        nqy[k] = -qpts[3 * qi + 1];
        nqz[k] = -qpts[3 * qi + 2];
        dmin[k] = 1e30f;
        imin[k] = 0;
    }

#pragma unroll 2
    for (int j = 0; j < RC; j++) {
        float4 r = sref[j];
#pragma unroll
        for (int k = 0; k < QPT; k++) {
            float s = fmaf(nqx[k], r.x, r.w);
            s = fmaf(nqy[k], r.y, s);
            s = fmaf(nqz[k], r.z, s);
            bool lt = s < dmin[k];          // strict < keeps earliest index
            dmin[k] = lt ? s : dmin[k];
            imin[k] = lt ? (refbase + j) : imin[k];
        }
    }

#pragma unroll
    for (int k = 0; k < QPT; k++) {
        unsigned u = __float_as_uint(dmin[k]);
        u = (u & 0x80000000u) ? ~u : (u | 0x80000000u);  // sortable float bits
        unsigned long long key =
            ((unsigned long long)u << 32) | (unsigned)imin[k];
        int qi = qbase + k * NTHREADS + tid;
        atomicMin(&best[qi], key);
    }
}

// Gather matched e-vectors, accumulate squared differences per block.
__global__ __launch_bounds__(NTHREADS) void loss_kernel(
    const unsigned long long* __restrict__ best_t2p,
    const unsigned long long* __restrict__ best_p2t,
    const float* __restrict__ pred_e, const float* __restrict__ trg_e,
    float* __restrict__ partials)
{
    const int tid = threadIdx.x;
    const int gid = blockIdx.x * NTHREADS + tid;
    const int stride = gridDim.x * NTHREADS;
    float acc = 0.0f;
    for (int i = gid; i < 2 * NV; i += stride) {
        const float* qe;
        const float* re;
        if (i < NV) {
            int idx = (int)(unsigned)(best_t2p[i] & 0xFFFFFFFFULL);
            qe = trg_e + 3 * i;
            re = pred_e + 3 * idx;
        } else {
            int q = i - NV;
            int idx = (int)(unsigned)(best_p2t[q] & 0xFFFFFFFFULL);
            qe = pred_e + 3 * q;
            re = trg_e + 3 * idx;
        }
        float dx = qe[0] - re[0];
        float dy = qe[1] - re[1];
        float dz = qe[2] - re[2];
        acc = fmaf(dx, dx, acc);
        acc = fmaf(dy, dy, acc);
        acc = fmaf(dz, dz, acc);
    }
    __shared__ float red[NTHREADS];
    red[tid] = acc;
    __syncthreads();
    for (int s = NTHREADS / 2; s > 0; s >>= 1) {
        if (tid < s) red[tid] += red[tid + s];
        __syncthreads();
    }
    if (tid == 0) partials[blockIdx.x] = red[0];
}

__global__ __launch_bounds__(LOSS_BLOCKS) void final_kernel(
    const float* __restrict__ partials, float* __restrict__ out)
{
    __shared__ float red[LOSS_BLOCKS];
    int tid = threadIdx.x;
    red[tid] = partials[tid];
    __syncthreads();
    for (int s = LOSS_BLOCKS / 2; s > 0; s >>= 1) {
        if (tid < s) red[tid] += red[tid + s];
        __syncthreads();
    }
    // Each loss is a mean over V*3 = 49152 elements; both share the divisor.
    if (tid == 0) out[0] = red[0] * (1.0f / 49152.0f);
}

extern "C" void kernel_launch(void* const* d_in, const int* in_sizes, int n_in,
                              void* d_out, int out_size, void* d_ws, size_t ws_size,
                              hipStream_t stream) {
    const float* pred_v = (const float*)d_in[0];
    const float* trg_v  = (const float*)d_in[1];
    const float* pred_e = (const float*)d_in[2];
    const float* trg_e  = (const float*)d_in[3];
    float* out = (float*)d_out;

    unsigned long long* best = (unsigned long long*)d_ws;   // 2*NV u64
    float* partials = (float*)(best + 2 * NV);              // LOSS_BLOCKS floats

    init_best_kernel<<<(2 * NV + NTHREADS - 1) / NTHREADS, NTHREADS, 0, stream>>>(best);

    // trg -> pred: queries = trg vertices, refs = pred vertices
    nn_kernel<<<dim3(QBLOCKS, RBLOCKS), NTHREADS, 0, stream>>>(trg_v, pred_v, best);
    // pred -> trg: queries = pred vertices, refs = trg vertices
    nn_kernel<<<dim3(QBLOCKS, RBLOCKS), NTHREADS, 0, stream>>>(pred_v, trg_v, best + NV);

    loss_kernel<<<LOSS_BLOCKS, NTHREADS, 0, stream>>>(best, best + NV, pred_e, trg_e, partials);
    final_kernel<<<1, LOSS_BLOCKS, 0, stream>>>(partials, out);
}

// Round 2
// 64.812 us; speedup vs baseline: 1.4880x; 1.4880x over previous
//
#include <hip/hip_runtime.h>

#define NV 16384
#define NT 256
#define QPT 4                      // queries per thread (pass 1)
#define RC 256                     // reference points per chunk
#define QBLOCKS (NV / (NT * QPT))  // 16
#define RBLOCKS (NV / RC)          // 64
#define LOSS_BLOCKS 128

__device__ __forceinline__ unsigned sortable(float f) {
    unsigned u = __float_as_uint(f);
    return (u & 0x80000000u) ? ~u : (u | 0x80000000u);
}

// Pass 1: per query, min metric over this block's 256-ref chunk.
// Metric: 0.5*||r||^2 - q.r (monotone-equivalent to squared distance).
// Merge across chunks: atomicMin of (sortable_dist << 32 | chunk_id).
// Lower chunk id wins ties -> matches argmin first-occurrence (the first
// occurrence of the global min lies in the lowest chunk holding it).
__global__ __launch_bounds__(NT) void nn_kernel(
    const float* __restrict__ qpts, const float* __restrict__ rpts,
    unsigned long long* __restrict__ best)
{
    __shared__ float4 sref[RC];
    const int tid = threadIdx.x;
    const int refbase = blockIdx.y * RC;

    for (int i = tid; i < RC; i += NT) {
        float x = rpts[3 * (refbase + i) + 0];
        float y = rpts[3 * (refbase + i) + 1];
        float z = rpts[3 * (refbase + i) + 2];
        float rw = 0.5f * fmaf(z, z, fmaf(y, y, x * x));
        sref[i] = make_float4(x, y, z, rw);
    }
    __syncthreads();

    const int qbase = blockIdx.x * (NT * QPT);
    float nqx[QPT], nqy[QPT], nqz[QPT], dmin[QPT];
#pragma unroll
    for (int k = 0; k < QPT; k++) {
        int qi = qbase + k * NT + tid;
        nqx[k] = -qpts[3 * qi + 0];
        nqy[k] = -qpts[3 * qi + 1];
        nqz[k] = -qpts[3 * qi + 2];
        dmin[k] = 1e30f;
    }

#pragma unroll 4
    for (int j = 0; j < RC; j += 2) {
        float4 r0 = sref[j];
        float4 r1 = sref[j + 1];
#pragma unroll
        for (int k = 0; k < QPT; k++) {
            float s0 = fmaf(nqx[k], r0.x, r0.w);
            s0 = fmaf(nqy[k], r0.y, s0);
            s0 = fmaf(nqz[k], r0.z, s0);
            float s1 = fmaf(nqx[k], r1.x, r1.w);
            s1 = fmaf(nqy[k], r1.y, s1);
            s1 = fmaf(nqz[k], r1.z, s1);
            dmin[k] = fminf(fminf(s0, s1), dmin[k]);  // v_min3_f32
        }
    }

#pragma unroll
    for (int k = 0; k < QPT; k++) {
        int qi = qbase + k * NT + tid;
        unsigned long long key =
            ((unsigned long long)sortable(dmin[k]) << 32) | (unsigned)blockIdx.y;
        atomicMin(&best[qi], key);
    }
}

// Pass 2: one wave per query. Rescan the winning 256-ref chunk, exact argmin
// with first-occurrence tie-break (strict < per lane over increasing j, then
// packed-u64 min across lanes picks lowest index on equal distance).
__global__ __launch_bounds__(NT) void resolve_kernel(
    const float* __restrict__ trg_v, const float* __restrict__ pred_v,
    const unsigned long long* __restrict__ best, int* __restrict__ idxout)
{
    const int dir = blockIdx.y;                 // 0: trg->pred, 1: pred->trg
    const float* qpts = dir ? pred_v : trg_v;
    const float* rpts = dir ? trg_v : pred_v;
    const unsigned long long* b = best + dir * NV;
    int* out = idxout + dir * NV;

    const int tid = threadIdx.x;
    const int lane = tid & 63;
    const int q = blockIdx.x * (NT / 64) + (tid >> 6);

    const int chunk = (int)(unsigned)(b[q] & 0xFFFFFFFFULL);
    const int base = chunk * RC;

    float nqx = -qpts[3 * q + 0];
    float nqy = -qpts[3 * q + 1];
    float nqz = -qpts[3 * q + 2];

    float dmin = 1e30f;
    int imin = base;
#pragma unroll
    for (int t = 0; t < RC / 64; t++) {
        int i = base + t * 64 + lane;
        float x = rpts[3 * i + 0];
        float y = rpts[3 * i + 1];
        float z = rpts[3 * i + 2];
        float rw = 0.5f * fmaf(z, z, fmaf(y, y, x * x));
        float s = fmaf(nqx, x, rw);
        s = fmaf(nqy, y, s);
        s = fmaf(nqz, z, s);
        bool lt = s < dmin;   // strict: keep earliest i within lane
        dmin = lt ? s : dmin;
        imin = lt ? i : imin;
    }
    unsigned long long key =
        ((unsigned long long)sortable(dmin) << 32) | (unsigned)imin;
#pragma unroll
    for (int off = 32; off > 0; off >>= 1) {
        unsigned long long o = __shfl_xor(key, off);
        key = (o < key) ? o : key;
    }
    if (lane == 0) out[q] = (int)(unsigned)(key & 0xFFFFFFFFULL);
}

__global__ __launch_bounds__(NT) void loss_kernel(
    const int* __restrict__ idx, const float* __restrict__ pred_e,
    const float* __restrict__ trg_e, float* __restrict__ partials)
{
    const int tid = threadIdx.x;
    const int i = blockIdx.x * NT + tid;   // 32768 threads, one element each
    float acc = 0.0f;
    {
        const float* qe;
        const float* re;
        if (i < NV) {
            int j = idx[i];                // trg -> pred
            qe = trg_e + 3 * i;
            re = pred_e + 3 * j;
        } else {
            int qq = i - NV;
            int j = idx[i];                // pred -> trg (idx offset NV)
            qe = pred_e + 3 * qq;
            re = trg_e + 3 * j;
        }
        float dx = qe[0] - re[0];
        float dy = qe[1] - re[1];
        float dz = qe[2] - re[2];
        acc = fmaf(dx, dx, acc);
        acc = fmaf(dy, dy, acc);
        acc = fmaf(dz, dz, acc);
    }
    __shared__ float red[NT];
    red[tid] = acc;
    __syncthreads();
    for (int s = NT / 2; s > 0; s >>= 1) {
        if (tid < s) red[tid] += red[tid + s];
        __syncthreads();
    }
    if (tid == 0) partials[blockIdx.x] = red[0];
}

__global__ __launch_bounds__(LOSS_BLOCKS) void final_kernel(
    const float* __restrict__ partials, float* __restrict__ out)
{
    __shared__ float red[LOSS_BLOCKS];
    int tid = threadIdx.x;
    red[tid] = partials[tid];
    __syncthreads();
    for (int s = LOSS_BLOCKS / 2; s > 0; s >>= 1) {
        if (tid < s) red[tid] += red[tid + s];
        __syncthreads();
    }
    if (tid == 0) out[0] = red[0] * (1.0f / 49152.0f);  // both losses: mean over V*3
}

extern "C" void kernel_launch(void* const* d_in, const int* in_sizes, int n_in,
                              void* d_out, int out_size, void* d_ws, size_t ws_size,
                              hipStream_t stream) {
    const float* pred_v = (const float*)d_in[0];
    const float* trg_v  = (const float*)d_in[1];
    const float* pred_e = (const float*)d_in[2];
    const float* trg_e  = (const float*)d_in[3];
    float* out = (float*)d_out;

    unsigned long long* best = (unsigned long long*)d_ws;   // 2*NV u64
    int* idx = (int*)(best + 2 * NV);                       // 2*NV int
    float* partials = (float*)(idx + 2 * NV);               // 128 floats

    hipMemsetAsync(best, 0xFF, 2 * NV * sizeof(unsigned long long), stream);

    // dir 0: queries = trg vertices, refs = pred vertices
    nn_kernel<<<dim3(QBLOCKS, RBLOCKS), NT, 0, stream>>>(trg_v, pred_v, best);
    // dir 1: queries = pred vertices, refs = trg vertices
    nn_kernel<<<dim3(QBLOCKS, RBLOCKS), NT, 0, stream>>>(pred_v, trg_v, best + NV);

    resolve_kernel<<<dim3(NV / (NT / 64), 2), NT, 0, stream>>>(trg_v, pred_v, best, idx);

    loss_kernel<<<LOSS_BLOCKS, NT, 0, stream>>>(idx, pred_e, trg_e, partials);
    final_kernel<<<1, LOSS_BLOCKS, 0, stream>>>(partials, out);
}

// Round 3
// 62.032 us; speedup vs baseline: 1.5547x; 1.0448x over previous
//
#include <hip/hip_runtime.h>

#define NV 16384
#define NT 256
#define QPT 4                      // queries per thread (pass 1)
#define RC 256                     // reference points per chunk
#define QBLOCKS (NV / (NT * QPT))  // 16
#define RBLOCKS (NV / RC)          // 64
#define RES_QPB (NT / 64)          // queries per resolve block (4)
#define RES_BLOCKS (NV / RES_QPB)  // 4096 per direction
#define NPART (2 * RES_BLOCKS)     // 8192 partial sums

__device__ __forceinline__ unsigned sortable(float f) {
    unsigned u = __float_as_uint(f);
    return (u & 0x80000000u) ? ~u : (u | 0x80000000u);
}

// Init best[] to +inf keys. (hipMemsetAsync's fill kernel cost 38 us in graph
// replay; this kernel does the same 256 KB in ~2 us.)
__global__ __launch_bounds__(NT) void init_kernel(unsigned long long* __restrict__ best) {
    int i = blockIdx.x * NT + threadIdx.x;
    best[i] = 0xFFFFFFFFFFFFFFFFULL;
    best[i + NV] = 0xFFFFFFFFFFFFFFFFULL;
}

// Pass 1, both directions (blockIdx.z): per query, min metric over this
// block's 256-ref chunk. Metric: 0.5*||r||^2 - q.r (monotone-equivalent to
// squared distance for fixed q). Merge across chunks via atomicMin of
// (sortable_dist << 32 | chunk_id); lower chunk wins ties -> matches argmin
// first-occurrence (first occurrence of the global min is in the lowest
// chunk that attains it).
__global__ __launch_bounds__(NT) void nn_kernel(
    const float* __restrict__ pred_v, const float* __restrict__ trg_v,
    unsigned long long* __restrict__ best)
{
    const int dir = blockIdx.z;            // 0: trg->pred, 1: pred->trg
    const float* qpts = dir ? pred_v : trg_v;
    const float* rpts = dir ? trg_v : pred_v;
    unsigned long long* b = best + dir * NV;

    __shared__ float4 sref[RC];
    const int tid = threadIdx.x;
    const int refbase = blockIdx.y * RC;

    for (int i = tid; i < RC; i += NT) {
        float x = rpts[3 * (refbase + i) + 0];
        float y = rpts[3 * (refbase + i) + 1];
        float z = rpts[3 * (refbase + i) + 2];
        float rw = 0.5f * fmaf(z, z, fmaf(y, y, x * x));
        sref[i] = make_float4(x, y, z, rw);
    }
    __syncthreads();

    const int qbase = blockIdx.x * (NT * QPT);
    float nqx[QPT], nqy[QPT], nqz[QPT], dmin[QPT];
#pragma unroll
    for (int k = 0; k < QPT; k++) {
        int qi = qbase + k * NT + tid;
        nqx[k] = -qpts[3 * qi + 0];
        nqy[k] = -qpts[3 * qi + 1];
        nqz[k] = -qpts[3 * qi + 2];
        dmin[k] = 1e30f;
    }

#pragma unroll 4
    for (int j = 0; j < RC; j += 2) {
        float4 r0 = sref[j];
        float4 r1 = sref[j + 1];
#pragma unroll
        for (int k = 0; k < QPT; k++) {
            float s0 = fmaf(nqx[k], r0.x, r0.w);
            s0 = fmaf(nqy[k], r0.y, s0);
            s0 = fmaf(nqz[k], r0.z, s0);
            float s1 = fmaf(nqx[k], r1.x, r1.w);
            s1 = fmaf(nqy[k], r1.y, s1);
            s1 = fmaf(nqz[k], r1.z, s1);
            dmin[k] = fminf(fminf(s0, s1), dmin[k]);  // v_min3_f32
        }
    }

#pragma unroll
    for (int k = 0; k < QPT; k++) {
        int qi = qbase + k * NT + tid;
        unsigned long long key =
            ((unsigned long long)sortable(dmin[k]) << 32) | (unsigned)blockIdx.y;
        atomicMin(&b[qi], key);
    }
}

// Pass 2 fused with loss: one wave per query. Rescan the winning chunk for
// the exact argmin (first-occurrence tie-break: strict < per lane over
// increasing i, then packed-u64 min across lanes picks lowest index on equal
// distance). Lane 0 then accumulates the e-vector squared error; block
// reduces deterministically to partials[].
__global__ __launch_bounds__(NT) void resolve_loss_kernel(
    const float* __restrict__ pred_v, const float* __restrict__ trg_v,
    const float* __restrict__ pred_e, const float* __restrict__ trg_e,
    const unsigned long long* __restrict__ best, float* __restrict__ partials)
{
    const int dir = blockIdx.y;            // 0: trg->pred, 1: pred->trg
    const float* qpts = dir ? pred_v : trg_v;
    const float* rpts = dir ? trg_v : pred_v;
    const float* qe_b = dir ? pred_e : trg_e;
    const float* re_b = dir ? trg_e : pred_e;
    const unsigned long long* b = best + dir * NV;

    const int tid = threadIdx.x;
    const int lane = tid & 63;
    const int wv = tid >> 6;
    const int q = blockIdx.x * RES_QPB + wv;

    const int chunk = (int)(unsigned)(b[q] & 0xFFFFFFFFULL);
    const int base = chunk * RC;

    float nqx = -qpts[3 * q + 0];
    float nqy = -qpts[3 * q + 1];
    float nqz = -qpts[3 * q + 2];

    float dmin = 1e30f;
    int imin = base;
#pragma unroll
    for (int t = 0; t < RC / 64; t++) {
        int i = base + t * 64 + lane;
        float x = rpts[3 * i + 0];
        float y = rpts[3 * i + 1];
        float z = rpts[3 * i + 2];
        float rw = 0.5f * fmaf(z, z, fmaf(y, y, x * x));
        float s = fmaf(nqx, x, rw);
        s = fmaf(nqy, y, s);
        s = fmaf(nqz, z, s);
        bool lt = s < dmin;   // strict: keep earliest i within lane
        dmin = lt ? s : dmin;
        imin = lt ? i : imin;
    }
    unsigned long long key =
        ((unsigned long long)sortable(dmin) << 32) | (unsigned)imin;
#pragma unroll
    for (int off = 32; off > 0; off >>= 1) {
        unsigned long long o = __shfl_xor(key, off);
        key = (o < key) ? o : key;
    }

    __shared__ float wsum[RES_QPB];
    if (lane == 0) {
        int j = (int)(unsigned)(key & 0xFFFFFFFFULL);
        float dx = qe_b[3 * q + 0] - re_b[3 * j + 0];
        float dy = qe_b[3 * q + 1] - re_b[3 * j + 1];
        float dz = qe_b[3 * q + 2] - re_b[3 * j + 2];
        wsum[wv] = fmaf(dx, dx, fmaf(dy, dy, dz * dz));
    }
    __syncthreads();
    if (tid == 0)
        partials[blockIdx.y * RES_BLOCKS + blockIdx.x] =
            (wsum[0] + wsum[1]) + (wsum[2] + wsum[3]);
}

__global__ __launch_bounds__(NT) void final_kernel(
    const float* __restrict__ partials, float* __restrict__ out)
{
    const int tid = threadIdx.x;
    float acc = 0.0f;
#pragma unroll
    for (int t = 0; t < NPART / NT; t++) acc += partials[t * NT + tid];
    __shared__ float red[NT];
    red[tid] = acc;
    __syncthreads();
    for (int s = NT / 2; s > 0; s >>= 1) {
        if (tid < s) red[tid] += red[tid + s];
        __syncthreads();
    }
    if (tid == 0) out[0] = red[0] * (1.0f / 49152.0f);  // both losses: mean over V*3
}

extern "C" void kernel_launch(void* const* d_in, const int* in_sizes, int n_in,
                              void* d_out, int out_size, void* d_ws, size_t ws_size,
                              hipStream_t stream) {
    const float* pred_v = (const float*)d_in[0];
    const float* trg_v  = (const float*)d_in[1];
    const float* pred_e = (const float*)d_in[2];
    const float* trg_e  = (const float*)d_in[3];
    float* out = (float*)d_out;

    unsigned long long* best = (unsigned long long*)d_ws;   // 2*NV u64
    float* partials = (float*)(best + 2 * NV);              // NPART floats

    init_kernel<<<NV / NT, NT, 0, stream>>>(best);

    nn_kernel<<<dim3(QBLOCKS, RBLOCKS, 2), NT, 0, stream>>>(pred_v, trg_v, best);

    resolve_loss_kernel<<<dim3(RES_BLOCKS, 2), NT, 0, stream>>>(
        pred_v, trg_v, pred_e, trg_e, best, partials);

    final_kernel<<<1, NT, 0, stream>>>(partials, out);
}

// Round 4
// 47.160 us; speedup vs baseline: 2.0450x; 1.3154x over previous
//
#include <hip/hip_runtime.h>
#include <hip/hip_bf16.h>

#define NV 16384
#define NT 256
#define NTILES 512                 // 32-point MFMA tiles per mesh
#define RT_CHUNK 64                // ref tiles per nn block
#define STG 16                     // tiles staged in LDS per round
#define RES_QPB 4                  // queries per resolve block (4 waves)
#define RES_BLOCKS (NV / RES_QPB)  // 4096 per direction
#define NPART (2 * RES_BLOCKS)     // 8192 partials

typedef __attribute__((ext_vector_type(8))) short bf16x8;
typedef __attribute__((ext_vector_type(16))) float f32x16;

__device__ __forceinline__ short bf16bits(float f) {
    __hip_bfloat16 h = __float2bfloat16(f);
    return *reinterpret_cast<short*>(&h);
}
__device__ __forceinline__ float bf16tof(short s) {
    __hip_bfloat16 h = *reinterpret_cast<__hip_bfloat16*>(&s);
    return __bfloat162float(h);
}
__device__ __forceinline__ unsigned sortable(float f) {
    unsigned u = __float_as_uint(f);
    return (u & 0x80000000u) ? ~u : (u | 0x80000000u);
}
__device__ __forceinline__ float min3f(float a, float b, float c) {
    float r;
    asm("v_min3_f32 %0, %1, %2, %3" : "=v"(r) : "v"(a), "v"(b), "v"(c));
    return r;
}

// min over the 32 metric values held in two 16-reg accumulators (one lane).
__device__ __forceinline__ float tile_min32(const f32x16& a, const f32x16& b) {
    float t0 = min3f(a[0], a[1], a[2]);
    float t1 = min3f(a[3], a[4], a[5]);
    float t2 = min3f(a[6], a[7], a[8]);
    float t3 = min3f(a[9], a[10], a[11]);
    float t4 = min3f(a[12], a[13], a[14]);
    float t5 = min3f(a[15], b[0], b[1]);
    float t6 = min3f(b[2], b[3], b[4]);
    float t7 = min3f(b[5], b[6], b[7]);
    float t8 = min3f(b[8], b[9], b[10]);
    float t9 = min3f(b[11], b[12], b[13]);
    float ta = fminf(b[14], b[15]);
    float s0 = min3f(t0, t1, t2);
    float s1 = min3f(t3, t4, t5);
    float s2 = min3f(t6, t7, t8);
    float s3 = min3f(t9, ta, s0);
    return min3f(s1, s2, s3);
}

// Pack MFMA fragments for both directions + init best[].
// Metric m(ref,query) = 0.5*||r||^2 - q.r computed via one K=11 MFMA:
//   A(ref) k-slots:   [rh.x rh.y rh.z | rl.x rl.y rl.z | rh.x rh.y rh.z | nh nl | 0...]
//   B(query) k-slots: [-qh.x -qh.y -qh.z | -qh.x -qh.y -qh.z | -ql.x -ql.y -ql.z | 1 1 | 0...]
// where vh = bf16(v), vl = bf16(v - float(vh)), n = 0.5*||r||^2 (fp32 split nh+nl).
// Any consistent lane->k permutation cancels since we pack A and B identically.
// Fragment memory layout per tile: 64 lanes x 8 bf16 (16 B), lane l = row/col l&31,
// k-half l>>5 -> loadable as one coalesced 16 B/lane vector.
__global__ __launch_bounds__(NT) void prep_kernel(
    const float* __restrict__ pred_v, const float* __restrict__ trg_v,
    short* __restrict__ Apack, short* __restrict__ Bpack,
    unsigned long long* __restrict__ best)
{
    int gid = blockIdx.x * NT + threadIdx.x;     // 0 .. 131071
    if (gid < 2 * NV) best[gid] = 0xFFFFFFFFFFFFFFFFULL;

    int role = gid >> 16;          // 0 = A (refs), 1 = B (queries)
    int rem  = gid & 0xFFFF;
    int d    = rem >> 15;          // direction: 0 trg->pred, 1 pred->trg
    int t    = (rem >> 6) & 511;   // tile
    int l    = rem & 63;           // lane slot
    int pt   = l & 31;
    int half = l >> 5;

    const float* src = (role == 0) ? (d ? trg_v : pred_v)   // refs
                                   : (d ? pred_v : trg_v);  // queries
    int p = t * 32 + pt;
    float x = src[3 * p + 0], y = src[3 * p + 1], z = src[3 * p + 2];

    bf16x8 v;
    if (role == 0) {
        short hx = bf16bits(x), hy = bf16bits(y), hz = bf16bits(z);
        short lx = bf16bits(x - bf16tof(hx));
        short ly = bf16bits(y - bf16tof(hy));
        short lz = bf16bits(z - bf16tof(hz));
        float n  = 0.5f * fmaf(z, z, fmaf(y, y, x * x));
        short nh = bf16bits(n);
        short nl = bf16bits(n - bf16tof(nh));
        if (half == 0) { v[0]=hx; v[1]=hy; v[2]=hz; v[3]=lx; v[4]=ly; v[5]=lz; v[6]=hx; v[7]=hy; }
        else           { v[0]=hz; v[1]=nh; v[2]=nl; v[3]=0; v[4]=0; v[5]=0; v[6]=0; v[7]=0; }
    } else {
        short hx = bf16bits(x), hy = bf16bits(y), hz = bf16bits(z);
        short nhx = bf16bits(-x), nhy = bf16bits(-y), nhz = bf16bits(-z);
        short nlx = bf16bits(bf16tof(hx) - x);   // -(x - hx)
        short nly = bf16bits(bf16tof(hy) - y);
        short nlz = bf16bits(bf16tof(hz) - z);
        const short one = 0x3F80;
        if (half == 0) { v[0]=nhx; v[1]=nhy; v[2]=nhz; v[3]=nhx; v[4]=nhy; v[5]=nhz; v[6]=nlx; v[7]=nly; }
        else           { v[0]=nlz; v[1]=one; v[2]=one; v[3]=0; v[4]=0; v[5]=0; v[6]=0; v[7]=0; }
    }
    short* dst = ((role == 0) ? Apack : Bpack) + (((size_t)(d * NTILES + t)) * 64 + l) * 8;
    *(bf16x8*)dst = v;
}

// Pass 1: MFMA all-pairs min. Block: 4 waves x 2 query-tiles each (8 qtiles),
// one 64-ref-tile chunk, one direction. LDS-stage A tiles (16 at a time),
// each wave: per ref tile-pair, 4 MFMAs + per-lane min3 tree; track
// (dmin, pairid) per query; merge lane halves; packed atomicMin.
__global__ __launch_bounds__(NT) void nn_mfma_kernel(
    const short* __restrict__ Apack, const short* __restrict__ Bpack,
    unsigned long long* __restrict__ best)
{
    __shared__ short lds[STG * 512];   // 16 KB
    const int tid = threadIdx.x, lane = tid & 63, w = tid >> 6;
    const int dir = blockIdx.z;
    const int qt0 = blockIdx.x * 8 + w * 2;
    const int rtb = blockIdx.y * RT_CHUNK;
    const size_t dbase = (size_t)dir * NTILES * 512;

    bf16x8 b0 = *(const bf16x8*)(Bpack + dbase + (size_t)qt0 * 512 + lane * 8);
    bf16x8 b1 = *(const bf16x8*)(Bpack + dbase + (size_t)(qt0 + 1) * 512 + lane * 8);

    float dmin0 = 1e30f, dmin1 = 1e30f;
    int bp0 = 0, bp1 = 0;

    for (int g = 0; g < RT_CHUNK / STG; g++) {
        __syncthreads();
        for (int t = w; t < STG; t += 4) {
            bf16x8 va = *(const bf16x8*)(Apack + dbase + (size_t)(rtb + g * STG + t) * 512 + lane * 8);
            *(bf16x8*)(&lds[t * 512 + lane * 8]) = va;
        }
        __syncthreads();
#pragma unroll
        for (int p = 0; p < STG / 2; p++) {
            bf16x8 a0 = *(const bf16x8*)(&lds[(2 * p) * 512 + lane * 8]);
            bf16x8 a1 = *(const bf16x8*)(&lds[(2 * p + 1) * 512 + lane * 8]);
            f32x16 zc = {};
            f32x16 c0 = __builtin_amdgcn_mfma_f32_32x32x16_bf16(a0, b0, zc, 0, 0, 0);
            f32x16 c1 = __builtin_amdgcn_mfma_f32_32x32x16_bf16(a1, b0, zc, 0, 0, 0);
            int pairid = blockIdx.y * 32 + g * (STG / 2) + p;
            float tm = tile_min32(c0, c1);
            bool lt = tm < dmin0; dmin0 = lt ? tm : dmin0; bp0 = lt ? pairid : bp0;
            f32x16 d0 = __builtin_amdgcn_mfma_f32_32x32x16_bf16(a0, b1, zc, 0, 0, 0);
            f32x16 d1 = __builtin_amdgcn_mfma_f32_32x32x16_bf16(a1, b1, zc, 0, 0, 0);
            tm = tile_min32(d0, d1);
            lt = tm < dmin1; dmin1 = lt ? tm : dmin1; bp1 = lt ? pairid : bp1;
        }
    }

    unsigned long long k0 = ((unsigned long long)sortable(dmin0) << 32) | (unsigned)bp0;
    unsigned long long k1 = ((unsigned long long)sortable(dmin1) << 32) | (unsigned)bp1;
    unsigned long long o0 = __shfl_xor(k0, 32); k0 = (o0 < k0) ? o0 : k0;
    unsigned long long o1 = __shfl_xor(k1, 32); k1 = (o1 < k1) ? o1 : k1;
    if (lane < 32) {
        atomicMin(&best[dir * NV + qt0 * 32 + lane], k0);
        atomicMin(&best[dir * NV + (qt0 + 1) * 32 + lane], k1);
    }
}

// Pass 2 + loss: wave per query; exact fp32 rescan of the winning 64-ref
// chunk (one lane per ref); packed-u64 argmin (first-occurrence tie-break);
// lane 0 accumulates e-vector MSE; deterministic block reduction.
__global__ __launch_bounds__(NT) void resolve_loss_kernel(
    const float* __restrict__ pred_v, const float* __restrict__ trg_v,
    const float* __restrict__ pred_e, const float* __restrict__ trg_e,
    const unsigned long long* __restrict__ best, float* __restrict__ partials)
{
    const int dir = blockIdx.y;
    const float* qpts = dir ? pred_v : trg_v;
    const float* rpts = dir ? trg_v : pred_v;
    const float* qe_b = dir ? pred_e : trg_e;
    const float* re_b = dir ? trg_e : pred_e;
    const unsigned long long* b = best + dir * NV;

    const int tid = threadIdx.x, lane = tid & 63, wv = tid >> 6;
    const int q = blockIdx.x * RES_QPB + wv;

    const int pair = (int)(unsigned)(b[q] & 0xFFFFFFFFULL);
    const int i = pair * 64 + lane;

    float nqx = -qpts[3 * q + 0], nqy = -qpts[3 * q + 1], nqz = -qpts[3 * q + 2];
    float x = rpts[3 * i + 0], y = rpts[3 * i + 1], z = rpts[3 * i + 2];
    float rw = 0.5f * fmaf(z, z, fmaf(y, y, x * x));
    float s = fmaf(nqx, x, rw);
    s = fmaf(nqy, y, s);
    s = fmaf(nqz, z, s);

    unsigned long long key = ((unsigned long long)sortable(s) << 32) | (unsigned)i;
#pragma unroll
    for (int off = 32; off > 0; off >>= 1) {
        unsigned long long o = __shfl_xor(key, off);
        key = (o < key) ? o : key;
    }

    __shared__ float wsum[RES_QPB];
    if (lane == 0) {
        int j = (int)(unsigned)(key & 0xFFFFFFFFULL);
        float dx = qe_b[3 * q + 0] - re_b[3 * j + 0];
        float dy = qe_b[3 * q + 1] - re_b[3 * j + 1];
        float dz = qe_b[3 * q + 2] - re_b[3 * j + 2];
        wsum[wv] = fmaf(dx, dx, fmaf(dy, dy, dz * dz));
    }
    __syncthreads();
    if (tid == 0)
        partials[dir * RES_BLOCKS + blockIdx.x] =
            (wsum[0] + wsum[1]) + (wsum[2] + wsum[3]);
}

__global__ __launch_bounds__(NT) void final_kernel(
    const float* __restrict__ partials, float* __restrict__ out)
{
    const int tid = threadIdx.x;
    float acc = 0.0f;
#pragma unroll
    for (int t = 0; t < NPART / NT; t++) acc += partials[t * NT + tid];
    __shared__ float red[NT];
    red[tid] = acc;
    __syncthreads();
    for (int s = NT / 2; s > 0; s >>= 1) {
        if (tid < s) red[tid] += red[tid + s];
        __syncthreads();
    }
    if (tid == 0) out[0] = red[0] * (1.0f / 49152.0f);  // both losses: mean over V*3
}

extern "C" void kernel_launch(void* const* d_in, const int* in_sizes, int n_in,
                              void* d_out, int out_size, void* d_ws, size_t ws_size,
                              hipStream_t stream) {
    const float* pred_v = (const float*)d_in[0];
    const float* trg_v  = (const float*)d_in[1];
    const float* pred_e = (const float*)d_in[2];
    const float* trg_e  = (const float*)d_in[3];
    float* out = (float*)d_out;

    unsigned long long* best = (unsigned long long*)d_ws;     // 2*NV u64 = 256 KB
    short* Apack = (short*)(best + 2 * NV);                   // 2*512*512 shorts = 1 MB
    short* Bpack = Apack + 2 * NTILES * 512;                  // 1 MB
    float* partials = (float*)(Bpack + 2 * NTILES * 512);     // 32 KB

    prep_kernel<<<(2 * 2 * NTILES * 64) / NT, NT, 0, stream>>>(pred_v, trg_v, Apack, Bpack, best);

    nn_mfma_kernel<<<dim3(NTILES / 8, NTILES / RT_CHUNK, 2), NT, 0, stream>>>(Apack, Bpack, best);

    resolve_loss_kernel<<<dim3(RES_BLOCKS, 2), NT, 0, stream>>>(
        pred_v, trg_v, pred_e, trg_e, best, partials);

    final_kernel<<<1, NT, 0, stream>>>(partials, out);
}

// Round 5
// 39.064 us; speedup vs baseline: 2.4688x; 1.2072x over previous
//
#include <hip/hip_runtime.h>
#include <hip/hip_bf16.h>

#define NV 16384
#define NT 256
#define NTILES 512                 // 32-point MFMA tiles per mesh
#define RT_CHUNK 64                // ref tiles per nn block
#define NCHUNK (NTILES / RT_CHUNK) // 8 chunks per direction
#define STG 32                     // tiles staged in LDS per round (32 KB)
#define RES_QPB 4                  // queries per resolve block (4 waves)
#define RES_BLOCKS (NV / RES_QPB)  // 4096 per direction
#define NPART (2 * RES_BLOCKS)     // 8192 partials

typedef __attribute__((ext_vector_type(8))) short bf16x8;
typedef __attribute__((ext_vector_type(16))) float f32x16;

__device__ __forceinline__ short bf16bits(float f) {
    __hip_bfloat16 h = __float2bfloat16(f);
    return *reinterpret_cast<short*>(&h);
}
__device__ __forceinline__ float bf16tof(short s) {
    __hip_bfloat16 h = *reinterpret_cast<__hip_bfloat16*>(&s);
    return __bfloat162float(h);
}
__device__ __forceinline__ unsigned sortable(float f) {
    unsigned u = __float_as_uint(f);
    return (u & 0x80000000u) ? ~u : (u | 0x80000000u);
}
__device__ __forceinline__ float min3f(float a, float b, float c) {
    float r;
    asm("v_min3_f32 %0, %1, %2, %3" : "=v"(r) : "v"(a), "v"(b), "v"(c));
    return r;
}
// min over the 16 f32 values of one MFMA accumulator (in-lane), 8 ops
__device__ __forceinline__ float tree16(const f32x16& c) {
    float t0 = min3f(c[0], c[1], c[2]);
    float t1 = min3f(c[3], c[4], c[5]);
    float t2 = min3f(c[6], c[7], c[8]);
    float t3 = min3f(c[9], c[10], c[11]);
    float t4 = min3f(c[12], c[13], c[14]);
    float s0 = min3f(t0, t1, c[15]);
    float s1 = min3f(t2, t3, t4);
    return fminf(s0, s1);
}

// MFMA fragment packing (K=11 of 16). Metric m(ref,query) = 0.5*||r||^2 - q.r:
//   A(ref) k:   [rh.x rh.y rh.z | rl.x rl.y rl.z | rh.x rh.y | rh.z nh nl | 0..]
//   B(query) k: [-qh.x -qh.y -qh.z | -qh.x -qh.y -qh.z | -ql.x -ql.y | -ql.z 1 1 | 0..]
// vh = bf16(v), vl = bf16(v - f32(vh)), n = 0.5||r||^2 split nh+nl.
// A and B use the same lane->k mapping so any permutation cancels.
__device__ __forceinline__ bf16x8 make_a(float x, float y, float z, int half) {
    short hx = bf16bits(x), hy = bf16bits(y), hz = bf16bits(z);
    short lx = bf16bits(x - bf16tof(hx));
    short ly = bf16bits(y - bf16tof(hy));
    short lz = bf16bits(z - bf16tof(hz));
    float n  = 0.5f * fmaf(z, z, fmaf(y, y, x * x));
    short nh = bf16bits(n);
    short nl = bf16bits(n - bf16tof(nh));
    bf16x8 v;
    v[0] = half ? hz : hx;  v[1] = half ? nh : hy;
    v[2] = half ? nl : hz;  v[3] = half ? (short)0 : lx;
    v[4] = half ? (short)0 : ly;  v[5] = half ? (short)0 : lz;
    v[6] = half ? (short)0 : hx;  v[7] = half ? (short)0 : hy;
    return v;
}
__device__ __forceinline__ bf16x8 make_b(float x, float y, float z, int half) {
    short hx = bf16bits(x), hy = bf16bits(y), hz = bf16bits(z);
    short nhx = bf16bits(-x), nhy = bf16bits(-y), nhz = bf16bits(-z);
    short nlx = bf16bits(bf16tof(hx) - x);
    short nly = bf16bits(bf16tof(hy) - y);
    short nlz = bf16bits(bf16tof(hz) - z);
    const short one = 0x3F80;
    bf16x8 v;
    v[0] = half ? nlz : nhx;  v[1] = half ? one : nhy;
    v[2] = half ? one : nhz;  v[3] = half ? (short)0 : nhx;
    v[4] = half ? (short)0 : nhy;  v[5] = half ? (short)0 : nhz;
    v[6] = half ? (short)0 : nlx;  v[7] = half ? (short)0 : nly;
    return v;
}

// Pass 1: self-contained MFMA all-pairs min. Block: 4 waves x 2 qtiles,
// one 64-rtile chunk, one direction. A fragments packed from raw points
// into LDS (2 rounds of 32 tiles); B fragments packed into registers.
// Per rtile: 2 MFMAs + two 8-op min3 trees; pair-track (dmin, pairid)
// at 64-ref granularity; merge lane halves; per-block store (no atomics).
__global__ __launch_bounds__(NT, 4) void nn_mfma_kernel(
    const float* __restrict__ pred_v, const float* __restrict__ trg_v,
    unsigned long long* __restrict__ results)
{
    __shared__ short lds[STG * 512];   // 32 KB
    const int tid = threadIdx.x, lane = tid & 63, w = tid >> 6;
    const int dir = blockIdx.z;
    const float* qpts = dir ? pred_v : trg_v;
    const float* rpts = dir ? trg_v : pred_v;
    const int qt0 = blockIdx.x * 8 + w * 2;
    const int rtb = blockIdx.y * RT_CHUNK;
    const int half = lane >> 5;

    const int qp0 = qt0 * 32 + (lane & 31);
    bf16x8 b0 = make_b(qpts[3 * qp0 + 0], qpts[3 * qp0 + 1], qpts[3 * qp0 + 2], half);
    bf16x8 b1 = make_b(qpts[3 * (qp0 + 32) + 0], qpts[3 * (qp0 + 32) + 1],
                       qpts[3 * (qp0 + 32) + 2], half);

    float dmin0 = 1e30f, dmin1 = 1e30f;
    int bp0 = 0, bp1 = 0;
    const f32x16 zc = {};

    for (int g = 0; g < RT_CHUNK / STG; g++) {
        __syncthreads();
        for (int s = tid; s < STG * 64; s += NT) {
            int t = s >> 6, l = s & 63;
            int rp = (rtb + g * STG + t) * 32 + (l & 31);
            bf16x8 va = make_a(rpts[3 * rp + 0], rpts[3 * rp + 1], rpts[3 * rp + 2], l >> 5);
            *(bf16x8*)(&lds[t * 512 + l * 8]) = va;
        }
        __syncthreads();
#pragma unroll 2
        for (int p = 0; p < STG / 2; p++) {
            bf16x8 a0 = *(const bf16x8*)(&lds[(2 * p) * 512 + lane * 8]);
            f32x16 c0 = __builtin_amdgcn_mfma_f32_32x32x16_bf16(a0, b0, zc, 0, 0, 0);
            f32x16 c1 = __builtin_amdgcn_mfma_f32_32x32x16_bf16(a0, b1, zc, 0, 0, 0);
            float u0 = tree16(c0), u1 = tree16(c1);
            bf16x8 a1 = *(const bf16x8*)(&lds[(2 * p + 1) * 512 + lane * 8]);
            f32x16 d0 = __builtin_amdgcn_mfma_f32_32x32x16_bf16(a1, b0, zc, 0, 0, 0);
            f32x16 d1 = __builtin_amdgcn_mfma_f32_32x32x16_bf16(a1, b1, zc, 0, 0, 0);
            float m0 = fminf(u0, tree16(d0));
            float m1 = fminf(u1, tree16(d1));
            int pid = blockIdx.y * (RT_CHUNK / 2) + g * (STG / 2) + p;
            bool lt0 = m0 < dmin0; dmin0 = lt0 ? m0 : dmin0; bp0 = lt0 ? pid : bp0;
            bool lt1 = m1 < dmin1; dmin1 = lt1 ? m1 : dmin1; bp1 = lt1 ? pid : bp1;
        }
    }

    unsigned long long k0 = ((unsigned long long)sortable(dmin0) << 32) | (unsigned)bp0;
    unsigned long long k1 = ((unsigned long long)sortable(dmin1) << 32) | (unsigned)bp1;
    unsigned long long o0 = __shfl_xor(k0, 32); k0 = (o0 < k0) ? o0 : k0;
    unsigned long long o1 = __shfl_xor(k1, 32); k1 = (o1 < k1) ? o1 : k1;
    if (lane < 32) {
        size_t base = ((size_t)dir * NCHUNK + blockIdx.y) * NV;
        results[base + qt0 * 32 + lane] = k0;
        results[base + (qt0 + 1) * 32 + lane] = k1;
    }
}

// Pass 2 + loss: wave per query. Min over the 8 chunk keys (shuffles; lowest
// pairid wins ties), exact fp32 rescan of the winning 64-ref pair (strict <
// per lane then packed-u64 lane-min -> first-occurrence argmin), lane 0
// accumulates e-vector MSE, deterministic block reduction.
__global__ __launch_bounds__(NT) void resolve_loss_kernel(
    const float* __restrict__ pred_v, const float* __restrict__ trg_v,
    const float* __restrict__ pred_e, const float* __restrict__ trg_e,
    const unsigned long long* __restrict__ results, float* __restrict__ partials)
{
    const int dir = blockIdx.y;
    const float* qpts = dir ? pred_v : trg_v;
    const float* rpts = dir ? trg_v : pred_v;
    const float* qe_b = dir ? pred_e : trg_e;
    const float* re_b = dir ? trg_e : pred_e;

    const int tid = threadIdx.x, lane = tid & 63, wv = tid >> 6;
    const int q = blockIdx.x * RES_QPB + wv;

    unsigned long long key = 0xFFFFFFFFFFFFFFFFULL;
    if (lane < NCHUNK)
        key = results[((size_t)dir * NCHUNK + lane) * NV + q];
    unsigned long long o;
    o = __shfl_xor(key, 4); key = (o < key) ? o : key;
    o = __shfl_xor(key, 2); key = (o < key) ? o : key;
    o = __shfl_xor(key, 1); key = (o < key) ? o : key;
    key = __shfl(key, 0);
    const int pair = (int)(unsigned)(key & 0xFFFFFFFFULL);
    const int i = pair * 64 + lane;

    float nqx = -qpts[3 * q + 0], nqy = -qpts[3 * q + 1], nqz = -qpts[3 * q + 2];
    float x = rpts[3 * i + 0], y = rpts[3 * i + 1], z = rpts[3 * i + 2];
    float rw = 0.5f * fmaf(z, z, fmaf(y, y, x * x));
    float s = fmaf(nqx, x, rw);
    s = fmaf(nqy, y, s);
    s = fmaf(nqz, z, s);

    unsigned long long kk = ((unsigned long long)sortable(s) << 32) | (unsigned)i;
#pragma unroll
    for (int off = 32; off > 0; off >>= 1) {
        unsigned long long t = __shfl_xor(kk, off);
        kk = (t < kk) ? t : kk;
    }

    __shared__ float wsum[RES_QPB];
    if (lane == 0) {
        int j = (int)(unsigned)(kk & 0xFFFFFFFFULL);
        float dx = qe_b[3 * q + 0] - re_b[3 * j + 0];
        float dy = qe_b[3 * q + 1] - re_b[3 * j + 1];
        float dz = qe_b[3 * q + 2] - re_b[3 * j + 2];
        wsum[wv] = fmaf(dx, dx, fmaf(dy, dy, dz * dz));
    }
    __syncthreads();
    if (tid == 0)
        partials[dir * RES_BLOCKS + blockIdx.x] =
            (wsum[0] + wsum[1]) + (wsum[2] + wsum[3]);
}

__global__ __launch_bounds__(NT) void final_kernel(
    const float* __restrict__ partials, float* __restrict__ out)
{
    const int tid = threadIdx.x;
    float acc = 0.0f;
#pragma unroll
    for (int t = 0; t < NPART / NT; t++) acc += partials[t * NT + tid];
    __shared__ float red[NT];
    red[tid] = acc;
    __syncthreads();
    for (int s = NT / 2; s > 0; s >>= 1) {
        if (tid < s) red[tid] += red[tid + s];
        __syncthreads();
    }
    if (tid == 0) out[0] = red[0] * (1.0f / 49152.0f);  // both losses: mean over V*3
}

extern "C" void kernel_launch(void* const* d_in, const int* in_sizes, int n_in,
                              void* d_out, int out_size, void* d_ws, size_t ws_size,
                              hipStream_t stream) {
    const float* pred_v = (const float*)d_in[0];
    const float* trg_v  = (const float*)d_in[1];
    const float* pred_e = (const float*)d_in[2];
    const float* trg_e  = (const float*)d_in[3];
    float* out = (float*)d_out;

    unsigned long long* results = (unsigned long long*)d_ws;  // 2*8*NV u64 = 2 MB
    float* partials = (float*)(results + 2 * NCHUNK * NV);    // 32 KB

    nn_mfma_kernel<<<dim3(NTILES / 8, NCHUNK, 2), NT, 0, stream>>>(pred_v, trg_v, results);

    resolve_loss_kernel<<<dim3(RES_BLOCKS, 2), NT, 0, stream>>>(
        pred_v, trg_v, pred_e, trg_e, results, partials);

    final_kernel<<<1, NT, 0, stream>>>(partials, out);
}